// Round 5
// baseline (629.229 us; speedup 1.0000x reference)
//
#include <hip/hip_runtime.h>

// ---------- types ----------
typedef __attribute__((ext_vector_type(8))) short short8;   // 8 bf16 (4 VGPRs)
typedef __attribute__((ext_vector_type(4))) float f32x4;    // MFMA accumulator

__device__ __forceinline__ unsigned short f2bf(float f) {
  union { float f; unsigned u; } x{f};
  unsigned r = x.u + 0x7FFFu + ((x.u >> 16) & 1u);  // round-to-nearest-even
  return (unsigned short)(r >> 16);
}

// async global->LDS, 16B per lane; LDS dest is wave-uniform base + lane*16
__device__ __forceinline__ void gload_lds16(const void* g, void* l) {
  __builtin_amdgcn_global_load_lds(
      (__attribute__((address_space(1))) void*)((unsigned long long)g),
      (__attribute__((address_space(3))) void*)(unsigned)((unsigned long long)l),
      16, 0, 0);
}

// 6-stage H64 butterfly over the first index of tile[64][64]
__device__ __forceinline__ void butterfly64(float (*tile)[64], int t) {
  const int c  = t & 63;
  const int pb = t >> 6;
#pragma unroll
  for (int h = 1; h < 64; h <<= 1) {
#pragma unroll
    for (int k = 0; k < 8; ++k) {
      const int p  = pb + (k << 2);
      const int j1 = ((p & ~(h - 1)) << 1) | (p & (h - 1));
      const int j2 = j1 + h;
      const float a = tile[j1][c], b = tile[j2][c];
      tile[j1][c] = a + b;
      tile[j2][c] = a - b;
    }
    __syncthreads();
  }
}

// ---------- K1: fused trellis decode + col-FWHT(low 6 bits of o) -> W[4096][4096] ----------
__global__ void k_deq_col1(const int* __restrict__ trellis,
                           const float* __restrict__ tlut,
                           float* __restrict__ W) {
  __shared__ unsigned short words[16][32];   // 16 tiles * 32 words
  __shared__ float tile[64][64];
  const int t  = threadIdx.x;
  const int rg = blockIdx.x >> 6;            // o-group (64 rows)
  const int cg = blockIdx.x & 63;            // i-group (64 cols)
#pragma unroll
  for (int r = 0; r < 2; ++r) {
    const int ff = t + (r << 8);
    const int a = ff >> 7, rw = ff & 127;
    const int src = ((rg * 4 + a) * 256 + cg * 4) * 32 + rw;
    ((unsigned short*)words)[a * 128 + rw] = (unsigned short)(trellis[src] & 0xFFFF);
  }
  __syncthreads();
#pragma unroll
  for (int r = 0; r < 8; ++r) {
    const int f  = t + (r << 8);
    const int tl = f >> 7, s = f & 127;
    const unsigned short* w = words[tl];
    unsigned state = 0;
#pragma unroll
    for (int j = 0; j < 4; ++j) {
      const int ss = (s - j) & 127;
      state |= (((unsigned)w[ss >> 2] >> (12 - 4 * (ss & 3))) & 0xFu) << (4 * j);
    }
    const float2 v = *(const float2*)(tlut + (size_t)state * 2);
    const int o = ((tl >> 2) << 4) + (s >> 3);
    const int i = ((tl & 3) << 4) + ((s & 7) << 1);
    tile[o][i]     = v.x;
    tile[o][i + 1] = v.y;
  }
  __syncthreads();
  butterfly64(tile, t);
  const size_t base = ((size_t)(rg * 64)) * 4096 + cg * 64;
#pragma unroll
  for (int k = 0; k < 4; ++k) {
    const int idx = t + (k << 8);
    const int r = idx >> 4, c4 = idx & 15;
    *(float4*)(W + base + (size_t)r * 4096 + (c4 << 2)) = *(float4*)(&tile[r][c4 << 2]);
  }
}

// ---------- K2: FWHT over rows (i axis, full H4096), in place, * 1/64 ----------
__global__ void k_fwht_row(float* __restrict__ W) {
  __shared__ float row[4096];
  const int t = threadIdx.x;
  float* g = W + ((size_t)blockIdx.x << 12);
#pragma unroll
  for (int k = 0; k < 4; ++k) {
    const int e = (t + (k << 8)) << 2;
    *(float4*)(row + e) = *(const float4*)(g + e);
  }
  __syncthreads();
  for (int h = 1; h < 4096; h <<= 1) {
#pragma unroll
    for (int k = 0; k < 8; ++k) {
      const int p  = t + (k << 8);
      const int j1 = ((p & ~(h - 1)) << 1) | (p & (h - 1));
      const int j2 = j1 + h;
      const float a = row[j1], b = row[j2];
      row[j1] = a + b;
      row[j2] = a - b;
    }
    __syncthreads();
  }
#pragma unroll
  for (int k = 0; k < 4; ++k) {
    const int e = (t + (k << 8)) << 2;
    float4 v = *(float4*)(row + e);
    v.x *= 0.015625f; v.y *= 0.015625f; v.z *= 0.015625f; v.w *= 0.015625f;
    *(float4*)(g + e) = v;
  }
}

// ---------- K3: col FWHT, high 6 bits of o, *1/64, *SV[o]*SU[i], -> bf16 Mt[N][K] ----------
__global__ void k_fwht_col2(const float* __restrict__ W,
                            const float* __restrict__ SU,
                            const float* __restrict__ SV,
                            unsigned short* __restrict__ Mt) {
  __shared__ float tile[64][64];
  const int t  = threadIdx.x;
  const int b  = blockIdx.x >> 6;   // row residue (low bits)
  const int cg = blockIdx.x & 63;
#pragma unroll
  for (int k = 0; k < 4; ++k) {
    const int idx = t + (k << 8);
    const int a = idx >> 4, c4 = idx & 15;
    const int row = (a << 6) + b;
    *(float4*)(&tile[a][c4 << 2]) =
        *(const float4*)(W + (size_t)row * 4096 + ((size_t)cg << 6) + (c4 << 2));
  }
  __syncthreads();
  butterfly64(tile, t);
#pragma unroll
  for (int k = 0; k < 4; ++k) {
    const int idx = t + (k << 8);
    const int a = idx >> 4, c4 = idx & 15;
    const int row = (a << 6) + b;                 // o (OUT index)
    const int col0 = (cg << 6) + (c4 << 2);       // i (IN index)
    const float sv = SV[row] * 0.015625f;
    const float4 su = *(const float4*)(SU + col0);
    const float4 v = *(float4*)(&tile[a][c4 << 2]);
    ushort4 o;
    o.x = f2bf(v.x * sv * su.x);
    o.y = f2bf(v.y * sv * su.y);
    o.z = f2bf(v.z * sv * su.z);
    o.w = f2bf(v.w * sv * su.w);
    *(ushort4*)(Mt + (size_t)row * 4096 + col0) = o;
  }
}

// ---------- K4: x fp32 -> bf16 ----------
__global__ void k_cvt_x(const float* __restrict__ x, unsigned short* __restrict__ xb) {
  const long long n4 = (long long)16384 * 4096 / 4;
  long long i = (long long)blockIdx.x * blockDim.x + threadIdx.x;
  const long long stride = (long long)gridDim.x * blockDim.x;
  for (; i < n4; i += stride) {
    const float4 v = *(const float4*)(x + i * 4);
    ushort4 o;
    o.x = f2bf(v.x); o.y = f2bf(v.y); o.z = f2bf(v.z); o.w = f2bf(v.w);
    *(ushort4*)(xb + i * 4) = o;
  }
}

// ---------- K5: 256x256 8-phase GEMM, SKEWED register pipeline ----------
// Phase p issues the ds_reads for phase p+1's MFMA (alternate kk register set),
// so the compiler's counted lgkm wait before each MFMA covers only the current
// in-flight reads: LDS service (~578 cyc/CU/phase) hides under the MFMA cluster
// (~620 cyc). Staging: 1 half-tile/phase; counted vmcnt(2) at phases 3 & 7 gates
// the newly staged K-tile (8 loads drained, 2 in flight). All LDS WAR hazards
// have >=1 barrier between last read and overwrite (derived per-buffer).
#define BARRIER __builtin_amdgcn_s_barrier()
#define WAITV4  asm volatile("s_waitcnt vmcnt(4)" ::: "memory")
#define WAITV2  asm volatile("s_waitcnt vmcnt(2)" ::: "memory")
#define WAITV0  asm volatile("s_waitcnt vmcnt(0)" ::: "memory")

#define STAGE_A(db, h, jj) do { \
  gload_lds16(aRow + (((size_t)((h)*128      )) << 12) + ((jj) << 6), smem +         (db)*32768 + (h)*16384 +        w1k); \
  gload_lds16(aRow + (((size_t)((h)*128 + 64 )) << 12) + ((jj) << 6), smem +         (db)*32768 + (h)*16384 + 8192 + w1k); \
} while (0)
#define STAGE_B(db, h, jj) do { \
  gload_lds16(bRow + (((size_t)((h)*128      )) << 12) + ((jj) << 6), smem + 65536 + (db)*32768 + (h)*16384 +        w1k); \
  gload_lds16(bRow + (((size_t)((h)*128 + 64 )) << 12) + ((jj) << 6), smem + 65536 + (db)*32768 + (h)*16384 + 8192 + w1k); \
} while (0)

#define RD_AF(kk, base, cx) do { _Pragma("unroll") \
  for (int mi = 0; mi < 8; ++mi) af[mi][kk] = *(const short8*)((base) + mi*2048 + (cx)); } while (0)
#define RD_B01(kk, base, cx) do { \
  bb[0][kk] = *(const short8*)((base) + 0*2048 + (cx)); \
  bb[1][kk] = *(const short8*)((base) + 1*2048 + (cx)); } while (0)
#define RD_B23(kk, base, cx) do { \
  bb[2][kk] = *(const short8*)((base) + 2*2048 + (cx)); \
  bb[3][kk] = *(const short8*)((base) + 3*2048 + (cx)); } while (0)

#define MMA01(kk) do { _Pragma("unroll") \
  for (int mi = 0; mi < 8; ++mi) { \
    acc[mi][0] = __builtin_amdgcn_mfma_f32_16x16x32_bf16(af[mi][kk], bb[0][kk], acc[mi][0], 0, 0, 0); \
    acc[mi][1] = __builtin_amdgcn_mfma_f32_16x16x32_bf16(af[mi][kk], bb[1][kk], acc[mi][1], 0, 0, 0); \
  } } while (0)
#define MMA23(kk) do { _Pragma("unroll") \
  for (int mi = 0; mi < 8; ++mi) { \
    acc[mi][2] = __builtin_amdgcn_mfma_f32_16x16x32_bf16(af[mi][kk], bb[2][kk], acc[mi][2], 0, 0, 0); \
    acc[mi][3] = __builtin_amdgcn_mfma_f32_16x16x32_bf16(af[mi][kk], bb[3][kk], acc[mi][3], 0, 0, 0); \
  } } while (0)

#define PHASE(READS, STAGE, WAIT, MMAC) do { \
  READS; STAGE; WAIT; \
  BARRIER; \
  __builtin_amdgcn_s_setprio(1); MMAC; __builtin_amdgcn_s_setprio(0); \
  BARRIER; \
} while (0)

__global__ void __launch_bounds__(512, 2)
k_gemm8(const unsigned short* __restrict__ A,
        const unsigned short* __restrict__ B,
        float* __restrict__ C) {
  extern __shared__ char smem[];
  const int t    = threadIdx.x;
  const int lane = t & 63, w = t >> 6;
  const int wr   = w >> 2, wc = w & 3;          // 2 x 4 wave grid
  const int hb   = wc >> 1, rb = (wc & 1) * 64; // B half / row base within half
  const int lr   = lane & 15, q = lane >> 4;
  const int w1k  = w * 1024;

  const int nt = blockIdx.x & 15;               // 16 N-tiles
  const int mt = blockIdx.x >> 4;               // 64 M-tiles

  // frag read offsets (bytes within a [128][64] half): row*128 + (chunk^(row&7))*16
  const int cx0 = lr * 128 + (((0 + q) ^ (lr & 7)) << 4);
  const int cx1 = lr * 128 + (((4 + q) ^ (lr & 7)) << 4);

  // LDS read bases
  const char* As0 = smem +         wr * 16384;            // A dbuf0, half=wr
  const char* As1 = smem + 32768 + wr * 16384;            // A dbuf1
  const char* Bs0 = smem + 65536 +         hb * 16384 + rb * 128;
  const char* Bs1 = smem + 65536 + 32768 + hb * 16384 + rb * 128;

  // staging source: row = (t>>3) within 64-row sub, chunk pre-swizzled c^(row&7)
  const int srow  = t >> 3;
  const int csrc8 = (((t & 7) ^ (srow & 7)) << 3);
  const unsigned short* aRow = A + (((size_t)(mt * 256 + srow)) << 12) + csrc8;
  const unsigned short* bRow = B + (((size_t)(nt * 256 + srow)) << 12) + csrc8;

  short8 af[8][2], bb[4][2];
  f32x4  acc[8][4];
#pragma unroll
  for (int i = 0; i < 8; ++i)
#pragma unroll
    for (int j = 0; j < 4; ++j) acc[i][j] = (f32x4){0.f, 0.f, 0.f, 0.f};

  // ---- prologue: dbuf0 <- K-tile 0 (4 HT), dbuf1 A <- K-tile 1 (2 HT) ----
  STAGE_A(0, 0, 0); STAGE_A(0, 1, 0); STAGE_B(0, 0, 0); STAGE_B(0, 1, 0);
  STAGE_A(1, 0, 1); STAGE_A(1, 1, 1);
  WAITV4;           // K-tile 0 landed; dbuf1-A (4 loads) may remain in flight
  BARRIER;
  // pre-reads for phase 1's MMA01(0): kk=0 slice of dbuf0
  RD_AF(0, As0, cx0); RD_B01(0, Bs0, cx0);

  for (int g = 0; g < 31; ++g) {
    const int jv = 2 * g + 1, ju2 = 2 * g + 2, jv2 = 2 * g + 3;
    // ---- K-tile 2g (dbuf0), K-tile 2g+1 (dbuf1); reads one phase ahead ----
    PHASE({ RD_B23(0, Bs0, cx0); },                    STAGE_B(1, 0, jv),  ,       MMA01(0));
    PHASE({ RD_AF(1, As0, cx1); RD_B01(1, Bs0, cx1); },STAGE_B(1, 1, jv),  ,       MMA23(0));
    PHASE({ RD_B23(1, Bs0, cx1); },                    STAGE_A(0, 0, ju2), WAITV2, MMA01(1));
    PHASE({ RD_AF(0, As1, cx0); RD_B01(0, Bs1, cx0); },STAGE_A(0, 1, ju2), ,       MMA23(1));
    PHASE({ RD_B23(0, Bs1, cx0); },                    STAGE_B(0, 0, ju2), ,       MMA01(0));
    PHASE({ RD_AF(1, As1, cx1); RD_B01(1, Bs1, cx1); },STAGE_B(0, 1, ju2), ,       MMA23(0));
    PHASE({ RD_B23(1, Bs1, cx1); },                    STAGE_A(1, 0, jv2), WAITV2, MMA01(1));
    PHASE({ RD_AF(0, As0, cx0); RD_B01(0, Bs0, cx0); },STAGE_A(1, 1, jv2), ,       MMA23(1));
  }
  // ---- tail group g=31: K-tiles 62 (dbuf0), 63 (dbuf1); only B(63) to stage ----
  PHASE({ RD_B23(0, Bs0, cx0); },                    STAGE_B(1, 0, 63), ,       MMA01(0));
  PHASE({ RD_AF(1, As0, cx1); RD_B01(1, Bs0, cx1); },STAGE_B(1, 1, 63), ,       MMA23(0));
  PHASE({ RD_B23(1, Bs0, cx1); },                    ,                  WAITV0, MMA01(1));
  PHASE({ RD_AF(0, As1, cx0); RD_B01(0, Bs1, cx0); },,                  ,       MMA23(1));
  PHASE({ RD_B23(0, Bs1, cx0); },                    ,                  ,       MMA01(0));
  PHASE({ RD_AF(1, As1, cx1); RD_B01(1, Bs1, cx1); },,                  ,       MMA23(0));
  PHASE({ RD_B23(1, Bs1, cx1); },                    ,                  ,       MMA01(1));
  PHASE({ },                                         ,                  ,       MMA23(1));

  // epilogue: C/D layout col=lane&15, row=(lane>>4)*4+reg
  float* cbase = C + (((size_t)(mt * 256 + wr * 128 + q * 4)) << 12)
               + nt * 256 + wc * 64 + lr;
#pragma unroll
  for (int mi = 0; mi < 8; ++mi)
#pragma unroll
    for (int ni = 0; ni < 4; ++ni)
#pragma unroll
      for (int r = 0; r < 4; ++r)
        cbase[(((size_t)(mi * 16 + r)) << 12) + ni * 16] = acc[mi][ni][r];
}

extern "C" void kernel_launch(void* const* d_in, const int* in_sizes, int n_in,
                              void* d_out, int out_size, void* d_ws, size_t ws_size,
                              hipStream_t stream) {
  const float* x       = (const float*)d_in[0];   // (8,2048,4096) fp32
  const int*   trellis = (const int*)d_in[1];     // (65536,32) int32
  const float* tlut    = (const float*)d_in[2];   // (65536,2) fp32
  const float* SU      = (const float*)d_in[3];   // (4096,)
  const float* SV      = (const float*)d_in[4];   // (4096,)
  float* out = (float*)d_out;

  char* ws = (char*)d_ws;
  float*          W  = (float*)ws;                            // 64 MiB fp32
  unsigned short* Mt = (unsigned short*)(ws + (64ull << 20)); // 32 MiB bf16 [N][K]
  unsigned short* xb = (unsigned short*)(ws + (96ull << 20)); // 128 MiB bf16 [M][K]

  hipFuncSetAttribute(reinterpret_cast<const void*>(&k_gemm8),
                      hipFuncAttributeMaxDynamicSharedMemorySize, 131072);

  hipLaunchKernelGGL(k_deq_col1,  dim3(4096),  dim3(256), 0, stream, trellis, tlut, W);
  hipLaunchKernelGGL(k_fwht_row,  dim3(4096),  dim3(256), 0, stream, W);
  hipLaunchKernelGGL(k_fwht_col2, dim3(4096),  dim3(256), 0, stream, W, SU, SV, Mt);
  hipLaunchKernelGGL(k_cvt_x,     dim3(2048),  dim3(256), 0, stream, x, xb);
  hipLaunchKernelGGL(k_gemm8,     dim3(1024),  dim3(512), 131072, stream, xb, Mt, out);
}

// Round 6
// 622.248 us; speedup vs baseline: 1.0112x; 1.0112x over previous
//
#include <hip/hip_runtime.h>

// ---------- types ----------
typedef __attribute__((ext_vector_type(8))) short short8;   // 8 bf16 (4 VGPRs)
typedef __attribute__((ext_vector_type(4))) float f32x4;    // MFMA accumulator

__device__ __forceinline__ unsigned short f2bf(float f) {
  union { float f; unsigned u; } x{f};
  unsigned r = x.u + 0x7FFFu + ((x.u >> 16) & 1u);  // round-to-nearest-even
  return (unsigned short)(r >> 16);
}

// async global->LDS, 16B per lane; LDS dest is wave-uniform base + lane*16
__device__ __forceinline__ void gload_lds16(const void* g, void* l) {
  __builtin_amdgcn_global_load_lds(
      (__attribute__((address_space(1))) void*)((unsigned long long)g),
      (__attribute__((address_space(3))) void*)(unsigned)((unsigned long long)l),
      16, 0, 0);
}

// 6-stage H64 butterfly over the first index of tile[64][64]
__device__ __forceinline__ void butterfly64(float (*tile)[64], int t) {
  const int c  = t & 63;
  const int pb = t >> 6;
#pragma unroll
  for (int h = 1; h < 64; h <<= 1) {
#pragma unroll
    for (int k = 0; k < 8; ++k) {
      const int p  = pb + (k << 2);
      const int j1 = ((p & ~(h - 1)) << 1) | (p & (h - 1));
      const int j2 = j1 + h;
      const float a = tile[j1][c], b = tile[j2][c];
      tile[j1][c] = a + b;
      tile[j2][c] = a - b;
    }
    __syncthreads();
  }
}

// ---------- K1: fused trellis decode + col-FWHT(low 6 bits of o) -> W[4096][4096] ----------
__global__ void k_deq_col1(const int* __restrict__ trellis,
                           const float* __restrict__ tlut,
                           float* __restrict__ W) {
  __shared__ unsigned short words[16][32];   // 16 tiles * 32 words
  __shared__ float tile[64][64];
  const int t  = threadIdx.x;
  const int rg = blockIdx.x >> 6;            // o-group (64 rows)
  const int cg = blockIdx.x & 63;            // i-group (64 cols)
#pragma unroll
  for (int r = 0; r < 2; ++r) {
    const int ff = t + (r << 8);
    const int a = ff >> 7, rw = ff & 127;
    const int src = ((rg * 4 + a) * 256 + cg * 4) * 32 + rw;
    ((unsigned short*)words)[a * 128 + rw] = (unsigned short)(trellis[src] & 0xFFFF);
  }
  __syncthreads();
#pragma unroll
  for (int r = 0; r < 8; ++r) {
    const int f  = t + (r << 8);
    const int tl = f >> 7, s = f & 127;
    const unsigned short* w = words[tl];
    unsigned state = 0;
#pragma unroll
    for (int j = 0; j < 4; ++j) {
      const int ss = (s - j) & 127;
      state |= (((unsigned)w[ss >> 2] >> (12 - 4 * (ss & 3))) & 0xFu) << (4 * j);
    }
    const float2 v = *(const float2*)(tlut + (size_t)state * 2);
    const int o = ((tl >> 2) << 4) + (s >> 3);
    const int i = ((tl & 3) << 4) + ((s & 7) << 1);
    tile[o][i]     = v.x;
    tile[o][i + 1] = v.y;
  }
  __syncthreads();
  butterfly64(tile, t);
  const size_t base = ((size_t)(rg * 64)) * 4096 + cg * 64;
#pragma unroll
  for (int k = 0; k < 4; ++k) {
    const int idx = t + (k << 8);
    const int r = idx >> 4, c4 = idx & 15;
    *(float4*)(W + base + (size_t)r * 4096 + (c4 << 2)) = *(float4*)(&tile[r][c4 << 2]);
  }
}

// ---------- K2: FWHT over rows (i axis, full H4096), in place, * 1/64 ----------
__global__ void k_fwht_row(float* __restrict__ W) {
  __shared__ float row[4096];
  const int t = threadIdx.x;
  float* g = W + ((size_t)blockIdx.x << 12);
#pragma unroll
  for (int k = 0; k < 4; ++k) {
    const int e = (t + (k << 8)) << 2;
    *(float4*)(row + e) = *(const float4*)(g + e);
  }
  __syncthreads();
  for (int h = 1; h < 4096; h <<= 1) {
#pragma unroll
    for (int k = 0; k < 8; ++k) {
      const int p  = t + (k << 8);
      const int j1 = ((p & ~(h - 1)) << 1) | (p & (h - 1));
      const int j2 = j1 + h;
      const float a = row[j1], b = row[j2];
      row[j1] = a + b;
      row[j2] = a - b;
    }
    __syncthreads();
  }
#pragma unroll
  for (int k = 0; k < 4; ++k) {
    const int e = (t + (k << 8)) << 2;
    float4 v = *(float4*)(row + e);
    v.x *= 0.015625f; v.y *= 0.015625f; v.z *= 0.015625f; v.w *= 0.015625f;
    *(float4*)(g + e) = v;
  }
}

// ---------- K3: col FWHT, high 6 bits of o, *1/64, *SV[o]*SU[i], -> bf16 Mt[N][K] ----------
__global__ void k_fwht_col2(const float* __restrict__ W,
                            const float* __restrict__ SU,
                            const float* __restrict__ SV,
                            unsigned short* __restrict__ Mt) {
  __shared__ float tile[64][64];
  const int t  = threadIdx.x;
  const int b  = blockIdx.x >> 6;   // row residue (low bits)
  const int cg = blockIdx.x & 63;
#pragma unroll
  for (int k = 0; k < 4; ++k) {
    const int idx = t + (k << 8);
    const int a = idx >> 4, c4 = idx & 15;
    const int row = (a << 6) + b;
    *(float4*)(&tile[a][c4 << 2]) =
        *(const float4*)(W + (size_t)row * 4096 + ((size_t)cg << 6) + (c4 << 2));
  }
  __syncthreads();
  butterfly64(tile, t);
#pragma unroll
  for (int k = 0; k < 4; ++k) {
    const int idx = t + (k << 8);
    const int a = idx >> 4, c4 = idx & 15;
    const int row = (a << 6) + b;                 // o (OUT index)
    const int col0 = (cg << 6) + (c4 << 2);       // i (IN index)
    const float sv = SV[row] * 0.015625f;
    const float4 su = *(const float4*)(SU + col0);
    const float4 v = *(float4*)(&tile[a][c4 << 2]);
    ushort4 o;
    o.x = f2bf(v.x * sv * su.x);
    o.y = f2bf(v.y * sv * su.y);
    o.z = f2bf(v.z * sv * su.z);
    o.w = f2bf(v.w * sv * su.w);
    *(ushort4*)(Mt + (size_t)row * 4096 + col0) = o;
  }
}

// ---------- K4: x fp32 -> bf16 ----------
__global__ void k_cvt_x(const float* __restrict__ x, unsigned short* __restrict__ xb) {
  const long long n4 = (long long)16384 * 4096 / 4;
  long long i = (long long)blockIdx.x * blockDim.x + threadIdx.x;
  const long long stride = (long long)gridDim.x * blockDim.x;
  for (; i < n4; i += stride) {
    const float4 v = *(const float4*)(x + i * 4);
    ushort4 o;
    o.x = f2bf(v.x); o.y = f2bf(v.y); o.z = f2bf(v.z); o.w = f2bf(v.w);
    *(ushort4*)(xb + i * 4) = o;
  }
}

// ---------- K5: 256x256 GEMM, FREE-RUN K-tiles (1 barrier / K-tile) ----------
// Per K-tile-64: vmcnt(0) (drains only the 8 staging loads issued one full tile
// earlier - already landed), ONE raw s_barrier (tile visible to all waves;
// previous-dbuf reads all consumed => WAR-safe), issue next tile's 8
// global_load_lds, then 24 ds_read_b128 + 64 MFMA free-run per wave with
// compiler-emitted graduated lgkm waits. No __syncthreads => no full-queue
// drain; 64 barriers total (vs 512 in the phase-locked version). Waves
// de-phase within a tile so LDS service overlaps the MFMA pipe (m114).
// T2 swizzle unchanged: pre-swizzled global source + same XOR on ds_read.
#define BARRIER __builtin_amdgcn_s_barrier()
#define WAITV0  asm volatile("s_waitcnt vmcnt(0)" ::: "memory")

#define STAGE_A(db, jj) do { \
  gload_lds16(aRow,                      smem +         (db)*32768 +         w1k + ((size_t)(jj) << 6)*2); \
  gload_lds16(aRow + ( 64ull << 12),     smem +         (db)*32768 +  8192 + w1k + ((size_t)(jj) << 6)*2); \
  gload_lds16(aRow + (128ull << 12),     smem +         (db)*32768 + 16384 + w1k + ((size_t)(jj) << 6)*2); \
  gload_lds16(aRow + (192ull << 12),     smem +         (db)*32768 + 24576 + w1k + ((size_t)(jj) << 6)*2); \
} while (0)
#define STAGE_B(db, jj) do { \
  gload_lds16(bRow,                      smem + 65536 + (db)*32768 +         w1k + ((size_t)(jj) << 6)*2); \
  gload_lds16(bRow + ( 64ull << 12),     smem + 65536 + (db)*32768 +  8192 + w1k + ((size_t)(jj) << 6)*2); \
  gload_lds16(bRow + (128ull << 12),     smem + 65536 + (db)*32768 + 16384 + w1k + ((size_t)(jj) << 6)*2); \
  gload_lds16(bRow + (192ull << 12),     smem + 65536 + (db)*32768 + 24576 + w1k + ((size_t)(jj) << 6)*2); \
} while (0)
// NOTE: jj-offset folded into the GLOBAL address instead (see aRowJ/bRowJ below).

#define RD_AF(kk, base, cx) do { _Pragma("unroll") \
  for (int mi = 0; mi < 8; ++mi) af[mi][kk] = *(const short8*)((base) + mi*2048 + (cx)); } while (0)
#define RD_BB(kk, base, cx) do { _Pragma("unroll") \
  for (int ni = 0; ni < 4; ++ni) bb[ni][kk] = *(const short8*)((base) + ni*2048 + (cx)); } while (0)

#define MMA_K(kk) do { _Pragma("unroll") \
  for (int mi = 0; mi < 8; ++mi) { \
    acc[mi][0] = __builtin_amdgcn_mfma_f32_16x16x32_bf16(af[mi][kk], bb[0][kk], acc[mi][0], 0, 0, 0); \
    acc[mi][1] = __builtin_amdgcn_mfma_f32_16x16x32_bf16(af[mi][kk], bb[1][kk], acc[mi][1], 0, 0, 0); \
    acc[mi][2] = __builtin_amdgcn_mfma_f32_16x16x32_bf16(af[mi][kk], bb[2][kk], acc[mi][2], 0, 0, 0); \
    acc[mi][3] = __builtin_amdgcn_mfma_f32_16x16x32_bf16(af[mi][kk], bb[3][kk], acc[mi][3], 0, 0, 0); \
  } } while (0)

// one K-tile: gate, barrier, stage next, free-run reads+MFMA
#define KTILE(Asx, Bsx, STAGES) do { \
  WAITV0; BARRIER; \
  STAGES; \
  RD_BB(0, Bsx, cx0); RD_AF(0, Asx, cx0); \
  __builtin_amdgcn_s_setprio(1); MMA_K(0); __builtin_amdgcn_s_setprio(0); \
  RD_BB(1, Bsx, cx1); RD_AF(1, Asx, cx1); \
  __builtin_amdgcn_s_setprio(1); MMA_K(1); __builtin_amdgcn_s_setprio(0); \
} while (0)

#define STAGE_ALL(db, jj) do { \
  const unsigned short* aJ = aRow + ((jj) << 6); \
  const unsigned short* bJ = bRow + ((jj) << 6); \
  gload_lds16(aJ,                  smem +         (db)*32768 +         w1k); \
  gload_lds16(aJ + ( 64ull << 12), smem +         (db)*32768 +  8192 + w1k); \
  gload_lds16(aJ + (128ull << 12), smem +         (db)*32768 + 16384 + w1k); \
  gload_lds16(aJ + (192ull << 12), smem +         (db)*32768 + 24576 + w1k); \
  gload_lds16(bJ,                  smem + 65536 + (db)*32768 +         w1k); \
  gload_lds16(bJ + ( 64ull << 12), smem + 65536 + (db)*32768 +  8192 + w1k); \
  gload_lds16(bJ + (128ull << 12), smem + 65536 + (db)*32768 + 16384 + w1k); \
  gload_lds16(bJ + (192ull << 12), smem + 65536 + (db)*32768 + 24576 + w1k); \
} while (0)

__global__ void __launch_bounds__(512, 2)
k_gemm8(const unsigned short* __restrict__ A,
        const unsigned short* __restrict__ B,
        float* __restrict__ C) {
  extern __shared__ char smem[];
  const int t    = threadIdx.x;
  const int lane = t & 63, w = t >> 6;
  const int wr   = w >> 2, wc = w & 3;          // 2 x 4 wave grid
  const int hb   = wc >> 1, rb = (wc & 1) * 64; // B half / row base within half
  const int lr   = lane & 15, q = lane >> 4;
  const int w1k  = w * 1024;

  const int nt = blockIdx.x & 15;               // 16 N-tiles
  const int mt = blockIdx.x >> 4;               // 64 M-tiles

  // frag read offsets (bytes within a [128][64] half): row*128 + (chunk^(row&7))*16
  const int cx0 = lr * 128 + (((0 + q) ^ (lr & 7)) << 4);
  const int cx1 = lr * 128 + (((4 + q) ^ (lr & 7)) << 4);

  // LDS read bases (LDS layout: A halves [2][128][64] per dbuf @0, B @64KiB)
  const char* As0 = smem +         wr * 16384;            // A dbuf0, half=wr
  const char* As1 = smem + 32768 + wr * 16384;            // A dbuf1
  const char* Bs0 = smem + 65536 +         hb * 16384 + rb * 128;
  const char* Bs1 = smem + 65536 + 32768 + hb * 16384 + rb * 128;

  // staging source: row = (t>>3) within 64-row sub, chunk pre-swizzled c^(row&7)
  const int srow  = t >> 3;
  const int csrc8 = (((t & 7) ^ (srow & 7)) << 3);
  const unsigned short* aRow = A + (((size_t)(mt * 256 + srow)) << 12) + csrc8;
  const unsigned short* bRow = B + (((size_t)(nt * 256 + srow)) << 12) + csrc8;

  short8 af[8][2], bb[4][2];
  f32x4  acc[8][4];
#pragma unroll
  for (int i = 0; i < 8; ++i)
#pragma unroll
    for (int j = 0; j < 4; ++j) acc[i][j] = (f32x4){0.f, 0.f, 0.f, 0.f};

  // prologue: stage K-tile 0 into dbuf0
  STAGE_ALL(0, 0);

  for (int g = 0; g < 31; ++g) {
    KTILE(As0, Bs0, STAGE_ALL(1, 2 * g + 1));   // compute tile 2g,   stage 2g+1
    KTILE(As1, Bs1, STAGE_ALL(0, 2 * g + 2));   // compute tile 2g+1, stage 2g+2
  }
  KTILE(As0, Bs0, STAGE_ALL(1, 63));            // compute tile 62, stage 63
  KTILE(As1, Bs1, {});                          // compute tile 63

  // epilogue: C/D layout col=lane&15, row=(lane>>4)*4+reg
  float* cbase = C + (((size_t)(mt * 256 + wr * 128 + q * 4)) << 12)
               + nt * 256 + wc * 64 + lr;
#pragma unroll
  for (int mi = 0; mi < 8; ++mi)
#pragma unroll
    for (int ni = 0; ni < 4; ++ni)
#pragma unroll
      for (int r = 0; r < 4; ++r)
        cbase[(((size_t)(mi * 16 + r)) << 12) + ni * 16] = acc[mi][ni][r];
}

extern "C" void kernel_launch(void* const* d_in, const int* in_sizes, int n_in,
                              void* d_out, int out_size, void* d_ws, size_t ws_size,
                              hipStream_t stream) {
  const float* x       = (const float*)d_in[0];   // (8,2048,4096) fp32
  const int*   trellis = (const int*)d_in[1];     // (65536,32) int32
  const float* tlut    = (const float*)d_in[2];   // (65536,2) fp32
  const float* SU      = (const float*)d_in[3];   // (4096,)
  const float* SV      = (const float*)d_in[4];   // (4096,)
  float* out = (float*)d_out;

  char* ws = (char*)d_ws;
  float*          W  = (float*)ws;                            // 64 MiB fp32
  unsigned short* Mt = (unsigned short*)(ws + (64ull << 20)); // 32 MiB bf16 [N][K]
  unsigned short* xb = (unsigned short*)(ws + (96ull << 20)); // 128 MiB bf16 [M][K]

  hipFuncSetAttribute(reinterpret_cast<const void*>(&k_gemm8),
                      hipFuncAttributeMaxDynamicSharedMemorySize, 131072);

  hipLaunchKernelGGL(k_deq_col1,  dim3(4096),  dim3(256), 0, stream, trellis, tlut, W);
  hipLaunchKernelGGL(k_fwht_row,  dim3(4096),  dim3(256), 0, stream, W);
  hipLaunchKernelGGL(k_fwht_col2, dim3(4096),  dim3(256), 0, stream, W, SU, SV, Mt);
  hipLaunchKernelGGL(k_cvt_x,     dim3(2048),  dim3(256), 0, stream, x, xb);
  hipLaunchKernelGGL(k_gemm8,     dim3(1024),  dim3(512), 131072, stream, xb, Mt, out);
}